// Round 2
// baseline (181.968 us; speedup 1.0000x reference)
//
#include <hip/hip_runtime.h>
#include <math.h>

#define NB 4
#define LL 4096
#define DD 1024
#define MM 256

typedef short s16x8 __attribute__((ext_vector_type(8)));
typedef short s16x4 __attribute__((ext_vector_type(4)));
typedef float fx4 __attribute__((ext_vector_type(4)));

__device__ __forceinline__ float b2f(short s) {
  union { unsigned u; float f; } v;
  v.u = ((unsigned)(unsigned short)s) << 16;
  return v.f;
}
__device__ __forceinline__ short f2b(float f) {
  union { float f; unsigned u; } v;
  v.f = f;
  unsigned r = (v.u + 0x7fffu + ((v.u >> 16) & 1u)) >> 16;
  return (short)(unsigned short)r;
}
// all MFMA LDS tiles have 64-element (128B) rows; XOR swizzle on 8-elem granule
__device__ __forceinline__ int swz(int row, int col) {
  return row * 64 + (col ^ ((row & 7) << 3));
}

typedef __attribute__((address_space(1))) const void* gas1_t;
typedef __attribute__((address_space(3))) void* las3_t;
#define GLL16(g, l) __builtin_amdgcn_global_load_lds((gas1_t)(const void*)(g), (las3_t)(void*)(l), 16, 0, 0)

// ---------------- cast fp32 -> bf16 (vectorized) ----------------
__global__ __launch_bounds__(256) void k_cast(const float* __restrict__ in, short* __restrict__ out, int n4) {
  int i = blockIdx.x * 256 + threadIdx.x;
  if (i >= n4) return;
  float4 v = ((const float4*)in)[i];
  s16x4 s;
  s[0] = f2b(v.x); s[1] = f2b(v.y); s[2] = f2b(v.z); s[3] = f2b(v.w);
  ((s16x4*)out)[i] = s;
}

// ---------------- V (B,L,D) fp32 -> VT (B,D,L) bf16 ----------------
__global__ __launch_bounds__(256) void k_vt(const float* __restrict__ V, short* __restrict__ VT) {
  __shared__ float t[64][65];
  int b = blockIdx.z, l0 = blockIdx.x * 64, d0 = blockIdx.y * 64;
  int tid = threadIdx.x;
  int r = tid >> 2, q = tid & 3;
  const float* src = V + ((size_t)b * LL + l0 + r) * DD + d0 + q * 16;
  #pragma unroll
  for (int i = 0; i < 16; i += 4) {
    float4 v = *(const float4*)(src + i);
    t[r][q * 16 + i + 0] = v.x;
    t[r][q * 16 + i + 1] = v.y;
    t[r][q * 16 + i + 2] = v.z;
    t[r][q * 16 + i + 3] = v.w;
  }
  __syncthreads();
  int a = tid & 31, dg = tid >> 5;
  #pragma unroll
  for (int j = 0; j < 8; ++j) {
    int d = dg * 8 + j;
    unsigned lo = (unsigned short)f2b(t[2 * a][d]);
    unsigned hi = (unsigned short)f2b(t[2 * a + 1][d]);
    *(unsigned*)(VT + ((size_t)b * DD + d0 + d) * LL + l0 + 2 * a) = lo | (hi << 16);
  }
}

// ---------------- rf GEMM: C(64,128) = X(64,1024) x Pb(m0:m0+128,1024)^T, exp epilogue ----------------
// blockIdx.z < NB: X=Q, out=rf_q (B,L,M) bf16, includes 1/sqrt(M)
// blockIdx.z >= NB: X=K, out=rf_kT (B,M,L) bf16 (transposed store via LDS bounce)
__global__ __launch_bounds__(256) void k_rf(const float* __restrict__ Q, const float* __restrict__ K,
                                            const short* __restrict__ Pb,
                                            short* __restrict__ rfq, short* __restrict__ rfkT) {
  __shared__ short Al[64 * 64];
  __shared__ short Bl[128 * 64];  // Pb tile; reused as transpose bounce in K mode
  int z = blockIdx.z;
  int mode = z >> 2, b = z & 3;
  int l0 = blockIdx.x * 64, m0 = blockIdx.y * 128;
  const float* X = mode ? K : Q;
  int tid = threadIdx.x, lane = tid & 63, w = tid >> 6;
  fx4 acc[4][2] = {};
  for (int d0 = 0; d0 < DD; d0 += 64) {
    // stage A: fp32 load (fully coalesced) -> bf16 -> swizzled LDS
    #pragma unroll
    for (int j = 0; j < 4; ++j) {
      int f4 = tid + j * 256, row = f4 >> 4, c4 = f4 & 15;
      float4 v = *(const float4*)(X + ((size_t)b * LL + l0 + row) * DD + d0 + c4 * 4);
      s16x4 s;
      s[0] = f2b(v.x); s[1] = f2b(v.y); s[2] = f2b(v.z); s[3] = f2b(v.w);
      *(s16x4*)&Al[row * 64 + ((c4 * 4) ^ ((row & 7) << 3))] = s;
    }
    // stage B: bf16 Pb via global_load_lds, source pre-swizzled (linear LDS dest)
    #pragma unroll
    for (int j = 0; j < 4; ++j) {
      int fl = tid + j * 256, row = fl >> 3, c8 = fl & 7;
      GLL16(Pb + (size_t)(m0 + row) * DD + d0 + (c8 ^ (row & 7)) * 8, &Bl[fl * 8]);
    }
    __syncthreads();
    #pragma unroll
    for (int ks = 0; ks < 2; ++ks) {
      int kb = ks * 32 + (lane >> 4) * 8;
      s16x8 af[4], bf[2];
      #pragma unroll
      for (int mi = 0; mi < 4; ++mi) af[mi] = *(const s16x8*)&Al[swz(mi * 16 + (lane & 15), kb)];
      #pragma unroll
      for (int ni = 0; ni < 2; ++ni) bf[ni] = *(const s16x8*)&Bl[swz(w * 32 + ni * 16 + (lane & 15), kb)];
      #pragma unroll
      for (int mi = 0; mi < 4; ++mi)
        #pragma unroll
        for (int ni = 0; ni < 2; ++ni)
          acc[mi][ni] = __builtin_amdgcn_mfma_f32_16x16x32_bf16(af[mi], bf[ni], acc[mi][ni], 0, 0, 0);
    }
    __syncthreads();
  }
  if (mode == 0) {
    #pragma unroll
    for (int mi = 0; mi < 4; ++mi)
      #pragma unroll
      for (int ni = 0; ni < 2; ++ni) {
        int r0 = mi * 16 + ((lane >> 4) << 2);
        int c = m0 + w * 32 + ni * 16 + (lane & 15);
        #pragma unroll
        for (int u = 0; u < 4; ++u)
          rfq[((size_t)b * LL + l0 + r0 + u) * MM + c] = f2b(expf(acc[mi][ni][u] * 0.03125f) * 0.0625f);
      }
  } else {
    // write C^T into Bl (swizzled by col-row), then coalesced store to (B,M,L)
    #pragma unroll
    for (int mi = 0; mi < 4; ++mi)
      #pragma unroll
      for (int ni = 0; ni < 2; ++ni) {
        int r0 = mi * 16 + ((lane >> 4) << 2);  // l within tile
        int c = w * 32 + ni * 16 + (lane & 15); // m within tile
        s16x4 s;
        #pragma unroll
        for (int u = 0; u < 4; ++u) s[u] = f2b(expf(acc[mi][ni][u] * 0.03125f));
        *(s16x4*)&Bl[c * 64 + (r0 ^ ((c & 7) << 3))] = s;
      }
    __syncthreads();
    #pragma unroll
    for (int j = 0; j < 16; ++j) {
      int m = j * 8 + (tid >> 5), a = tid & 31, rr = a * 2;
      unsigned uv = *(const unsigned*)&Bl[m * 64 + (rr ^ ((m & 7) << 3))];
      *(unsigned*)(rfkT + ((size_t)b * MM + m0 + m) * LL + l0 + rr) = uv;
    }
  }
}

// ---------------- Z[b][m] = sum_l rf_kT[b][m][l] ----------------
__global__ __launch_bounds__(256) void k_z(const short* __restrict__ rfkT, float* __restrict__ Z) {
  int g = blockIdx.x * 4 + (threadIdx.x >> 6);
  int lane = threadIdx.x & 63;
  int b = g >> 8, m = g & 255;
  const s16x8* p = (const s16x8*)(rfkT + ((size_t)b * MM + m) * LL);
  float s = 0.f;
  #pragma unroll
  for (int j = 0; j < 8; ++j) {
    s16x8 v = p[lane + j * 64];
    #pragma unroll
    for (int i = 0; i < 8; ++i) s += b2f(v[i]);
  }
  for (int off = 32; off; off >>= 1) s += __shfl_down(s, off);
  if (lane == 0) Z[b * MM + m] = s;
}

// ---------------- KVT[b][d][m] += sum_l VT[d][l]*rf_kT[m][l], split-K=16 atomics ----------------
__global__ __launch_bounds__(256) void k_kv(const short* __restrict__ VT, const short* __restrict__ rfkT,
                                            float* __restrict__ KVTf) {
  __shared__ short Avl[64 * 64];
  __shared__ short Bkl[256 * 64];
  int d0 = blockIdx.x * 64, kc = blockIdx.y, b = blockIdx.z;
  int tid = threadIdx.x, lane = tid & 63, w = tid >> 6;
  fx4 acc[4][4] = {};
  const short* Abase = VT + ((size_t)b * DD + d0) * LL + kc * 256;
  const short* Bbase = rfkT + ((size_t)b * MM) * LL + kc * 256;
  for (int it = 0; it < 4; ++it) {
    int lc = it * 64;
    #pragma unroll
    for (int j = 0; j < 2; ++j) {
      int fl = tid + j * 256, row = fl >> 3, c8 = fl & 7;
      GLL16(Abase + (size_t)row * LL + lc + (c8 ^ (row & 7)) * 8, &Avl[fl * 8]);
    }
    #pragma unroll
    for (int j = 0; j < 8; ++j) {
      int fl = tid + j * 256, row = fl >> 3, c8 = fl & 7;
      GLL16(Bbase + (size_t)row * LL + lc + (c8 ^ (row & 7)) * 8, &Bkl[fl * 8]);
    }
    __syncthreads();
    #pragma unroll
    for (int ks = 0; ks < 2; ++ks) {
      int kb = ks * 32 + (lane >> 4) * 8;
      s16x8 af[4], bf[4];
      #pragma unroll
      for (int mi = 0; mi < 4; ++mi) af[mi] = *(const s16x8*)&Avl[swz(mi * 16 + (lane & 15), kb)];
      #pragma unroll
      for (int ni = 0; ni < 4; ++ni) bf[ni] = *(const s16x8*)&Bkl[swz(w * 64 + ni * 16 + (lane & 15), kb)];
      #pragma unroll
      for (int mi = 0; mi < 4; ++mi)
        #pragma unroll
        for (int ni = 0; ni < 4; ++ni)
          acc[mi][ni] = __builtin_amdgcn_mfma_f32_16x16x32_bf16(af[mi], bf[ni], acc[mi][ni], 0, 0, 0);
    }
    __syncthreads();
  }
  #pragma unroll
  for (int mi = 0; mi < 4; ++mi)
    #pragma unroll
    for (int ni = 0; ni < 4; ++ni)
      #pragma unroll
      for (int u = 0; u < 4; ++u) {
        int dd2 = d0 + mi * 16 + ((lane >> 4) << 2) + u;
        int mm2 = w * 64 + ni * 16 + (lane & 15);
        atomicAdd(&KVTf[((size_t)b * DD + dd2) * MM + mm2], acc[mi][ni][u]);
      }
}

// ---------------- out = (rf_q x KVT^T) / (rf_q . Z + eps) ----------------
__global__ __launch_bounds__(512) void k_out(const short* __restrict__ rfq, const short* __restrict__ KVTb,
                                             const float* __restrict__ Z, float* __restrict__ out) {
  __shared__ short Aql[128 * 64];
  __shared__ short Bkv[128 * 64];
  __shared__ float zl[256];
  __shared__ float np[512];
  __shared__ float nf[128];
  int l0 = blockIdx.x * 128, d0 = blockIdx.y * 128, b = blockIdx.z;
  int tid = threadIdx.x, lane = tid & 63, w = tid >> 6;
  int wr = w >> 1, wc = w & 1;
  if (tid < 256) zl[tid] = Z[b * MM + tid];
  fx4 acc[2][4] = {};
  float na = 0.f;
  int nrow = tid & 127, nsub = tid >> 7;
  for (int it = 0; it < 4; ++it) {
    int m0 = it * 64;
    #pragma unroll
    for (int j = 0; j < 2; ++j) {
      int fl = tid + j * 512, row = fl >> 3, c8 = fl & 7;
      GLL16(rfq + ((size_t)b * LL + l0 + row) * MM + m0 + (c8 ^ (row & 7)) * 8, &Aql[fl * 8]);
    }
    #pragma unroll
    for (int j = 0; j < 2; ++j) {
      int fl = tid + j * 512, row = fl >> 3, c8 = fl & 7;
      GLL16(KVTb + ((size_t)b * DD + d0 + row) * MM + m0 + (c8 ^ (row & 7)) * 8, &Bkv[fl * 8]);
    }
    __syncthreads();
    // normalizer partial: 4 threads per row, 16 k each
    #pragma unroll
    for (int kk = 0; kk < 16; ++kk) {
      int k = nsub * 16 + kk;
      na += b2f(Aql[nrow * 64 + (k ^ ((nrow & 7) << 3))]) * zl[m0 + k];
    }
    #pragma unroll
    for (int ks = 0; ks < 2; ++ks) {
      int kb = ks * 32 + (lane >> 4) * 8;
      s16x8 af[2], bf[4];
      #pragma unroll
      for (int mi = 0; mi < 2; ++mi) af[mi] = *(const s16x8*)&Aql[swz(wr * 32 + mi * 16 + (lane & 15), kb)];
      #pragma unroll
      for (int ni = 0; ni < 4; ++ni) bf[ni] = *(const s16x8*)&Bkv[swz(wc * 64 + ni * 16 + (lane & 15), kb)];
      #pragma unroll
      for (int mi = 0; mi < 2; ++mi)
        #pragma unroll
        for (int ni = 0; ni < 4; ++ni)
          acc[mi][ni] = __builtin_amdgcn_mfma_f32_16x16x32_bf16(af[mi], bf[ni], acc[mi][ni], 0, 0, 0);
    }
    __syncthreads();
  }
  np[tid] = na;
  __syncthreads();
  if (tid < 128) nf[tid] = np[tid] + np[tid + 128] + np[tid + 256] + np[tid + 384] + 1e-6f;
  __syncthreads();
  #pragma unroll
  for (int mi = 0; mi < 2; ++mi)
    #pragma unroll
    for (int ni = 0; ni < 4; ++ni) {
      int r0 = wr * 32 + mi * 16 + ((lane >> 4) << 2);
      int c = d0 + wc * 64 + ni * 16 + (lane & 15);
      #pragma unroll
      for (int u = 0; u < 4; ++u)
        out[((size_t)b * LL + l0 + r0 + u) * DD + c] = acc[mi][ni][u] / nf[r0 + u];
    }
}

extern "C" void kernel_launch(void* const* d_in, const int* in_sizes, int n_in,
                              void* d_out, int out_size, void* d_ws, size_t ws_size,
                              hipStream_t stream) {
  const float* Q = (const float*)d_in[0];
  const float* K = (const float*)d_in[1];
  const float* V = (const float*)d_in[2];
  const float* P = (const float*)d_in[3];
  float* out = (float*)d_out;
  char* ws = (char*)d_ws;

  short* Pb   = (short*)(ws + 0);          // 256*1024*2      = 512 KB
  short* VT   = (short*)(ws + 524288);     // 4*1024*4096*2   = 32 MB
  short* rfq  = (short*)(ws + 34078720);   // 4*4096*256*2    = 8 MB
  short* rfkT = (short*)(ws + 42467328);   // 4*256*4096*2    = 8 MB
  float* Zz   = (float*)(ws + 50855936);   // 4*256*4         = 4 KB
  float* KVTf = (float*)(ws + 50860032);   // 4*1024*256*4    = 4 MB
  short* KVTb = (short*)(ws + 55054336);   // 4*1024*256*2    = 2 MB

  k_cast<<<256, 256, 0, stream>>>(P, Pb, 65536);
  k_vt<<<dim3(64, 16, NB), 256, 0, stream>>>(V, VT);
  k_rf<<<dim3(64, 2, 2 * NB), 256, 0, stream>>>(Q, K, Pb, rfq, rfkT);
  k_z<<<256, 256, 0, stream>>>(rfkT, Zz);
  (void)hipMemsetAsync(KVTf, 0, (size_t)NB * DD * MM * sizeof(float), stream);
  k_kv<<<dim3(16, 16, NB), 256, 0, stream>>>(VT, rfkT, KVTf);
  k_cast<<<1024, 256, 0, stream>>>(KVTf, KVTb, 262144);
  k_out<<<dim3(32, 8, NB), 512, 0, stream>>>(rfq, KVTb, Zz, out);
}

// Round 3
// 156.188 us; speedup vs baseline: 1.1651x; 1.1651x over previous
//
#include <hip/hip_runtime.h>
#include <math.h>

#define NB 4
#define LL 4096
#define DD 1024
#define MM 256

typedef short s16x8 __attribute__((ext_vector_type(8)));
typedef short s16x4 __attribute__((ext_vector_type(4)));
typedef float fx4 __attribute__((ext_vector_type(4)));
typedef unsigned u32x4 __attribute__((ext_vector_type(4)));

__device__ __forceinline__ float b2f(short s) {
  union { unsigned u; float f; } v;
  v.u = ((unsigned)(unsigned short)s) << 16;
  return v.f;
}
__device__ __forceinline__ short f2b(float f) {
  union { float f; unsigned u; } v;
  v.f = f;
  unsigned r = (v.u + 0x7fffu + ((v.u >> 16) & 1u)) >> 16;
  return (short)(unsigned short)r;
}
// packed fp32->bf16 (RNE), 2 values per instruction
__device__ __forceinline__ unsigned cvt2(float lo, float hi) {
  unsigned r;
  asm("v_cvt_pk_bf16_f32 %0, %1, %2" : "=v"(r) : "v"(lo), "v"(hi));
  return r;
}
// MFMA LDS tiles: 64-element (128B) rows, XOR swizzle on 8-elem granule
__device__ __forceinline__ int swz(int row, int col) {
  return row * 64 + (col ^ ((row & 7) << 3));
}

typedef __attribute__((address_space(1))) const void* gas1_t;
typedef __attribute__((address_space(3))) void* las3_t;
#define GLL16(g, l) __builtin_amdgcn_global_load_lds((gas1_t)(const void*)(g), (las3_t)(void*)(l), 16, 0, 0)

// ---------------- cast fp32 -> bf16 (P only) ----------------
__global__ __launch_bounds__(256) void k_cast(const float* __restrict__ in, short* __restrict__ out, int n4) {
  int i = blockIdx.x * 256 + threadIdx.x;
  if (i >= n4) return;
  float4 v = ((const float4*)in)[i];
  s16x4 s;
  s[0] = f2b(v.x); s[1] = f2b(v.y); s[2] = f2b(v.z); s[3] = f2b(v.w);
  ((s16x4*)out)[i] = s;
}

// ---------------- rf GEMM: 128l x 128m tile, K=1024, 2-phase dbuf ----------------
// mode 0 (z<4): rf_q (B,L,M) bf16 incl 1/sqrt(M);  mode 1: rf_kT (B,M,L) bf16 + Z atomics
__global__ __launch_bounds__(512) void k_rf(const float* __restrict__ Q, const float* __restrict__ K,
                                            const short* __restrict__ Pb,
                                            short* __restrict__ rfq, short* __restrict__ rfkT,
                                            float* __restrict__ Zz) {
  __shared__ short Al[2][8192];
  __shared__ short Bl[2][8192];
  int z = blockIdx.z, mode = z >> 2, b = z & 3;
  int l0 = blockIdx.x * 128, m0 = blockIdx.y * 128;
  const float* X = mode ? K : Q;
  int tid = threadIdx.x, lane = tid & 63, w = tid >> 6;
  int wr = w >> 2, wc = w & 3;             // wave grid: 2(l) x 4(m)
  // A staging: row = tid>>2 (128 rows), 16 k per thread
  int arow = tid >> 2, aq = (tid & 3) * 16;
  int akey = (arow & 7) << 3;
  const float* Xr = X + ((size_t)b * LL + l0 + arow) * DD + aq;
  short* Aw0 = &Al[0][arow * 64 + (aq ^ akey)];
  short* Aw1 = &Al[0][arow * 64 + ((aq + 8) ^ akey)];
  // B staging via GLL16: 128 rows x 64 k, 2 chunks
  int f1 = tid + 512;
  int br0 = tid >> 3, bc0 = tid & 7, br1 = f1 >> 3, bc1 = f1 & 7;
  const short* Pb0 = Pb + (size_t)(m0 + br0) * DD + (bc0 ^ (br0 & 7)) * 8;
  const short* Pb1 = Pb + (size_t)(m0 + br1) * DD + (bc1 ^ (br1 & 7)) * 8;

  fx4 acc[4][2] = {};
  float4 pa[4];

  // prologue: tile 0
  #pragma unroll
  for (int i = 0; i < 4; ++i) pa[i] = *(const float4*)(Xr + i * 4);
  GLL16(Pb0, &Bl[0][tid * 8]);
  GLL16(Pb1, &Bl[0][f1 * 8]);
  {
    u32x4 v0, v1;
    v0[0] = cvt2(pa[0].x, pa[0].y); v0[1] = cvt2(pa[0].z, pa[0].w);
    v0[2] = cvt2(pa[1].x, pa[1].y); v0[3] = cvt2(pa[1].z, pa[1].w);
    v1[0] = cvt2(pa[2].x, pa[2].y); v1[1] = cvt2(pa[2].z, pa[2].w);
    v1[2] = cvt2(pa[3].x, pa[3].y); v1[3] = cvt2(pa[3].z, pa[3].w);
    *(u32x4*)Aw0 = v0;
    *(u32x4*)Aw1 = v1;
  }
  __syncthreads();

  for (int t = 0; t < 16; ++t) {
    int cur = t & 1, nxt = cur ^ 1;
    int d1 = ((t + 1) & 15) * 64;  // wraps harmlessly on last iter
    // issue next-tile loads (T14: issue early)
    #pragma unroll
    for (int i = 0; i < 4; ++i) pa[i] = *(const float4*)(Xr + d1 + i * 4);
    GLL16(Pb0 + d1, &Bl[nxt][tid * 8]);
    GLL16(Pb1 + d1, &Bl[nxt][f1 * 8]);
    // compute current tile
    #pragma unroll
    for (int ks = 0; ks < 2; ++ks) {
      int kb = ks * 32 + (lane >> 4) * 8;
      s16x8 af[4], bf[2];
      #pragma unroll
      for (int mi = 0; mi < 4; ++mi) af[mi] = *(const s16x8*)&Al[cur][swz(wr * 64 + mi * 16 + (lane & 15), kb)];
      #pragma unroll
      for (int ni = 0; ni < 2; ++ni) bf[ni] = *(const s16x8*)&Bl[cur][swz(wc * 32 + ni * 16 + (lane & 15), kb)];
      #pragma unroll
      for (int mi = 0; mi < 4; ++mi)
        #pragma unroll
        for (int ni = 0; ni < 2; ++ni)
          acc[mi][ni] = __builtin_amdgcn_mfma_f32_16x16x32_bf16(af[mi], bf[ni], acc[mi][ni], 0, 0, 0);
    }
    // write next A tile (T14: write late)
    {
      u32x4 v0, v1;
      v0[0] = cvt2(pa[0].x, pa[0].y); v0[1] = cvt2(pa[0].z, pa[0].w);
      v0[2] = cvt2(pa[1].x, pa[1].y); v0[3] = cvt2(pa[1].z, pa[1].w);
      v1[0] = cvt2(pa[2].x, pa[2].y); v1[1] = cvt2(pa[2].z, pa[2].w);
      v1[2] = cvt2(pa[3].x, pa[3].y); v1[3] = cvt2(pa[3].z, pa[3].w);
      *(u32x4*)(Aw0 + nxt * 8192) = v0;
      *(u32x4*)(Aw1 + nxt * 8192) = v1;
    }
    __syncthreads();
  }

  if (mode == 0) {
    #pragma unroll
    for (int mi = 0; mi < 4; ++mi)
      #pragma unroll
      for (int ni = 0; ni < 2; ++ni) {
        int r0 = wr * 64 + mi * 16 + ((lane >> 4) << 2);
        int c = m0 + wc * 32 + ni * 16 + (lane & 15);
        #pragma unroll
        for (int u = 0; u < 4; ++u)
          rfq[((size_t)b * LL + l0 + r0 + u) * MM + c] = f2b(expf(acc[mi][ni][u] * 0.03125f) * 0.0625f);
      }
  } else {
    // transpose bounce into Al overlay [128m][128l], fused Z partial sums
    short* T = &Al[0][0];
    float zp0 = 0.f, zp1 = 0.f;
    #pragma unroll
    for (int mi = 0; mi < 4; ++mi)
      #pragma unroll
      for (int ni = 0; ni < 2; ++ni) {
        int lb = wr * 64 + mi * 16 + ((lane >> 4) << 2);
        int m = wc * 32 + ni * 16 + (lane & 15);
        s16x4 s;
        #pragma unroll
        for (int u = 0; u < 4; ++u) {
          float e = expf(acc[mi][ni][u] * 0.03125f);
          if (ni == 0) zp0 += e; else zp1 += e;
          s[u] = f2b(e);
        }
        *(s16x4*)&T[m * 128 + (lb ^ ((m & 7) << 3))] = s;
      }
    zp0 += __shfl_xor(zp0, 16); zp0 += __shfl_xor(zp0, 32);
    zp1 += __shfl_xor(zp1, 16); zp1 += __shfl_xor(zp1, 32);
    if ((lane >> 4) == 0) {
      atomicAdd(&Zz[b * MM + m0 + wc * 32 + lane], zp0);
      atomicAdd(&Zz[b * MM + m0 + wc * 32 + 16 + lane], zp1);
    }
    __syncthreads();
    int m = tid >> 2, sb = tid & 3;
    #pragma unroll
    for (int j = 0; j < 4; ++j) {
      int l = sb * 32 + j * 8;
      s16x8 v = *(const s16x8*)&T[m * 128 + (l ^ ((m & 7) << 3))];
      *(s16x8*)(rfkT + ((size_t)b * MM + m0 + m) * LL + l0 + l) = v;
    }
  }
}

// ---------------- KVT[b][d][m] += sum_l V^T[d][l]*rf_kT[m][l]; fused V transpose ----------------
__global__ __launch_bounds__(256) void k_kv(const float* __restrict__ V, const short* __restrict__ rfkT,
                                            float* __restrict__ KVTf) {
  __shared__ short Av[2][4096];   // [64 d][64 l]
  __shared__ short Bk[2][8192];   // [128 m][64 l]
  int bx = blockIdx.x;                       // 32: d-tile(16) x m-half(2)
  int d0 = (bx >> 1) * 64, m0 = (bx & 1) * 128;
  int kc = blockIdx.y, b = blockIdx.z;       // kc 0..7, l-chunk 512
  int tid = threadIdx.x, lane = tid & 63, w = tid >> 6;
  // A staging: 2 d-cols, 8 l per thread; column-coalesced float2 loads (256B/instr)
  int dcol = (tid & 31) * 2, lg = (tid >> 5) * 8;
  const float* Vb = V + ((size_t)b * LL + (size_t)kc * 512) * DD + d0 + dcol;
  int key0 = (dcol & 7) << 3, key1 = ((dcol + 1) & 7) << 3;
  const short* Bb = rfkT + ((size_t)b * MM + m0) * LL + (size_t)kc * 512;
  fx4 acc[4][2] = {};
  float2 pv[8];

  // prologue: tile 0
  #pragma unroll
  for (int j = 0; j < 8; ++j) pv[j] = *(const float2*)(Vb + (size_t)(lg + j) * DD);
  #pragma unroll
  for (int j = 0; j < 4; ++j) {
    int fl = tid + j * 256, row = fl >> 3, c8 = fl & 7;
    GLL16(Bb + (size_t)row * LL + (c8 ^ (row & 7)) * 8, &Bk[0][fl * 8]);
  }
  {
    u32x4 v0, v1;
    v0[0] = cvt2(pv[0].x, pv[1].x); v0[1] = cvt2(pv[2].x, pv[3].x);
    v0[2] = cvt2(pv[4].x, pv[5].x); v0[3] = cvt2(pv[6].x, pv[7].x);
    v1[0] = cvt2(pv[0].y, pv[1].y); v1[1] = cvt2(pv[2].y, pv[3].y);
    v1[2] = cvt2(pv[4].y, pv[5].y); v1[3] = cvt2(pv[6].y, pv[7].y);
    *(u32x4*)&Av[0][dcol * 64 + (lg ^ key0)] = v0;
    *(u32x4*)&Av[0][(dcol + 1) * 64 + (lg ^ key1)] = v1;
  }
  __syncthreads();

  for (int t = 0; t < 8; ++t) {
    int cur = t & 1, nxt = cur ^ 1;
    int l1 = ((t + 1) & 7) * 64;
    #pragma unroll
    for (int j = 0; j < 8; ++j) pv[j] = *(const float2*)(Vb + (size_t)(l1 + lg + j) * DD);
    #pragma unroll
    for (int j = 0; j < 4; ++j) {
      int fl = tid + j * 256, row = fl >> 3, c8 = fl & 7;
      GLL16(Bb + (size_t)row * LL + l1 + (c8 ^ (row & 7)) * 8, &Bk[nxt][fl * 8]);
    }
    #pragma unroll
    for (int ks = 0; ks < 2; ++ks) {
      int kb = ks * 32 + (lane >> 4) * 8;
      s16x8 af[4], bf[2];
      #pragma unroll
      for (int mi = 0; mi < 4; ++mi) af[mi] = *(const s16x8*)&Av[cur][swz(mi * 16 + (lane & 15), kb)];
      #pragma unroll
      for (int ni = 0; ni < 2; ++ni) bf[ni] = *(const s16x8*)&Bk[cur][swz(w * 32 + ni * 16 + (lane & 15), kb)];
      #pragma unroll
      for (int mi = 0; mi < 4; ++mi)
        #pragma unroll
        for (int ni = 0; ni < 2; ++ni)
          acc[mi][ni] = __builtin_amdgcn_mfma_f32_16x16x32_bf16(af[mi], bf[ni], acc[mi][ni], 0, 0, 0);
    }
    {
      u32x4 v0, v1;
      v0[0] = cvt2(pv[0].x, pv[1].x); v0[1] = cvt2(pv[2].x, pv[3].x);
      v0[2] = cvt2(pv[4].x, pv[5].x); v0[3] = cvt2(pv[6].x, pv[7].x);
      v1[0] = cvt2(pv[0].y, pv[1].y); v1[1] = cvt2(pv[2].y, pv[3].y);
      v1[2] = cvt2(pv[4].y, pv[5].y); v1[3] = cvt2(pv[6].y, pv[7].y);
      *(u32x4*)&Av[nxt][dcol * 64 + (lg ^ key0)] = v0;
      *(u32x4*)&Av[nxt][(dcol + 1) * 64 + (lg ^ key1)] = v1;
    }
    __syncthreads();
  }
  #pragma unroll
  for (int mi = 0; mi < 4; ++mi)
    #pragma unroll
    for (int ni = 0; ni < 2; ++ni) {
      int d = d0 + mi * 16 + ((lane >> 4) << 2);
      int m = m0 + w * 32 + ni * 16 + (lane & 15);
      #pragma unroll
      for (int u = 0; u < 4; ++u)
        atomicAdd(&KVTf[((size_t)b * DD + d + u) * MM + m], acc[mi][ni][u]);
    }
}

// ---------------- out = (rf_q x KVT^T) / (rf_q . Z + eps); KVTf read fp32 ----------------
__global__ __launch_bounds__(512) void k_out(const short* __restrict__ rfq, const float* __restrict__ KVTf,
                                             const float* __restrict__ Zz, float* __restrict__ out) {
  __shared__ short Aq[2][8192];   // [128 l][64 m]
  __shared__ short Bv[2][8192];   // [128 d][64 m]
  __shared__ float zl[256];
  __shared__ float np[512];
  __shared__ float nf[128];
  int l0 = blockIdx.x * 128, d0 = blockIdx.y * 128, b = blockIdx.z;
  int tid = threadIdx.x, lane = tid & 63, w = tid >> 6;
  int wr = w >> 2, wc = w & 3;               // 2(l) x 4(d)
  int brow = tid >> 2, bq = (tid & 3) * 16;
  int bkey = (brow & 7) << 3;
  const float* Kf = KVTf + ((size_t)b * DD + d0 + brow) * MM + bq;
  short* Bw0 = &Bv[0][brow * 64 + (bq ^ bkey)];
  short* Bw1 = &Bv[0][brow * 64 + ((bq + 8) ^ bkey)];
  const short* Ab = rfq + ((size_t)b * LL + l0) * MM;
  int f1 = tid + 512;
  int ar0 = tid >> 3, ac0 = tid & 7, ar1 = f1 >> 3, ac1 = f1 & 7;
  int nrow = tid & 127, nsub = tid >> 7;
  if (tid < 256) zl[tid] = Zz[b * MM + tid];
  fx4 acc[4][2] = {};
  float4 pb[4];
  float na = 0.f;

  // prologue: m-chunk 0
  #pragma unroll
  for (int i = 0; i < 4; ++i) pb[i] = *(const float4*)(Kf + i * 4);
  GLL16(Ab + (size_t)ar0 * MM + (ac0 ^ (ar0 & 7)) * 8, &Aq[0][tid * 8]);
  GLL16(Ab + (size_t)ar1 * MM + (ac1 ^ (ar1 & 7)) * 8, &Aq[0][f1 * 8]);
  {
    u32x4 v0, v1;
    v0[0] = cvt2(pb[0].x, pb[0].y); v0[1] = cvt2(pb[0].z, pb[0].w);
    v0[2] = cvt2(pb[1].x, pb[1].y); v0[3] = cvt2(pb[1].z, pb[1].w);
    v1[0] = cvt2(pb[2].x, pb[2].y); v1[1] = cvt2(pb[2].z, pb[2].w);
    v1[2] = cvt2(pb[3].x, pb[3].y); v1[3] = cvt2(pb[3].z, pb[3].w);
    *(u32x4*)Bw0 = v0;
    *(u32x4*)Bw1 = v1;
  }
  __syncthreads();

  for (int t = 0; t < 4; ++t) {
    int cur = t & 1, nxt = cur ^ 1;
    int m1 = ((t + 1) & 3) * 64;
    #pragma unroll
    for (int i = 0; i < 4; ++i) pb[i] = *(const float4*)(Kf + m1 + i * 4);
    GLL16(Ab + (size_t)ar0 * MM + m1 + (ac0 ^ (ar0 & 7)) * 8, &Aq[nxt][tid * 8]);
    GLL16(Ab + (size_t)ar1 * MM + m1 + (ac1 ^ (ar1 & 7)) * 8, &Aq[nxt][f1 * 8]);
    // normalizer partial: 4 threads per row, 16 k each
    #pragma unroll
    for (int kk = 0; kk < 16; ++kk) {
      int k = nsub * 16 + kk;
      na += b2f(Aq[cur][nrow * 64 + (k ^ ((nrow & 7) << 3))]) * zl[t * 64 + k];
    }
    #pragma unroll
    for (int ks = 0; ks < 2; ++ks) {
      int kb = ks * 32 + (lane >> 4) * 8;
      s16x8 af[4], bf[2];
      #pragma unroll
      for (int mi = 0; mi < 4; ++mi) af[mi] = *(const s16x8*)&Aq[cur][swz(wr * 64 + mi * 16 + (lane & 15), kb)];
      #pragma unroll
      for (int ni = 0; ni < 2; ++ni) bf[ni] = *(const s16x8*)&Bv[cur][swz(wc * 32 + ni * 16 + (lane & 15), kb)];
      #pragma unroll
      for (int mi = 0; mi < 4; ++mi)
        #pragma unroll
        for (int ni = 0; ni < 2; ++ni)
          acc[mi][ni] = __builtin_amdgcn_mfma_f32_16x16x32_bf16(af[mi], bf[ni], acc[mi][ni], 0, 0, 0);
    }
    {
      u32x4 v0, v1;
      v0[0] = cvt2(pb[0].x, pb[0].y); v0[1] = cvt2(pb[0].z, pb[0].w);
      v0[2] = cvt2(pb[1].x, pb[1].y); v0[3] = cvt2(pb[1].z, pb[1].w);
      v1[0] = cvt2(pb[2].x, pb[2].y); v1[1] = cvt2(pb[2].z, pb[2].w);
      v1[2] = cvt2(pb[3].x, pb[3].y); v1[3] = cvt2(pb[3].z, pb[3].w);
      *(u32x4*)(Bw0 + nxt * 8192) = v0;
      *(u32x4*)(Bw1 + nxt * 8192) = v1;
    }
    __syncthreads();
  }
  np[tid] = na;
  __syncthreads();
  if (tid < 128) nf[tid] = np[tid] + np[tid + 128] + np[tid + 256] + np[tid + 384] + 1e-6f;
  __syncthreads();
  #pragma unroll
  for (int mi = 0; mi < 4; ++mi)
    #pragma unroll
    for (int ni = 0; ni < 2; ++ni) {
      int l = wr * 64 + mi * 16 + ((lane >> 4) << 2);
      int d = d0 + wc * 32 + ni * 16 + (lane & 15);
      #pragma unroll
      for (int u = 0; u < 4; ++u)
        out[((size_t)b * LL + l0 + l + u) * DD + d] = acc[mi][ni][u] / nf[l + u];
    }
}

extern "C" void kernel_launch(void* const* d_in, const int* in_sizes, int n_in,
                              void* d_out, int out_size, void* d_ws, size_t ws_size,
                              hipStream_t stream) {
  const float* Q = (const float*)d_in[0];
  const float* K = (const float*)d_in[1];
  const float* V = (const float*)d_in[2];
  const float* P = (const float*)d_in[3];
  float* out = (float*)d_out;
  char* ws = (char*)d_ws;

  short* Pb   = (short*)(ws + 0);          // 256*1024*2    = 512 KB
  float* Zz   = (float*)(ws + 524288);     // 4*256*4       = 4 KB
  float* KVTf = (float*)(ws + 528384);     // 4*1024*256*4  = 4 MB
  short* rfq  = (short*)(ws + 4722688);    // 4*4096*256*2  = 8 MB
  short* rfkT = (short*)(ws + 13111296);   // 4*256*4096*2  = 8 MB

  k_cast<<<256, 256, 0, stream>>>(P, Pb, 65536);
  (void)hipMemsetAsync(ws + 524288, 0, 4096 + (size_t)NB * DD * MM * sizeof(float), stream);
  k_rf<<<dim3(32, 2, 2 * NB), 512, 0, stream>>>(Q, K, Pb, rfq, rfkT, Zz);
  k_kv<<<dim3(32, 8, NB), 256, 0, stream>>>(V, rfkT, KVTf);
  k_out<<<dim3(32, 8, NB), 512, 0, stream>>>(rfq, KVTf, Zz, out);
}